// Round 9
// baseline (290.258 us; speedup 1.0000x reference)
//
#include <hip/hip_runtime.h>
#include <hip/hip_bf16.h>
#include <stdint.h>

// B=1024, D_IN=2048, D_H=4096, D_OUT=2048, D_INT=1024
// Key algebra: F = m5.reshape(R,C) = H_R · Z · H_C with Z[i][j] = z[i*C+j],
// z = t[Pi&1023]*GG (gather only — no big WHT!).  x@F^T = ((x H_C) @ Z^T) H_R · sc.

typedef __attribute__((ext_vector_type(8))) short bf16x8;
typedef __attribute__((ext_vector_type(8))) short short8;
typedef __attribute__((ext_vector_type(4))) float f32x4;

__device__ __forceinline__ ushort f2bf(float f) {
  union { float f; uint32_t u; } v; v.f = f;
  return (ushort)((v.u + 0x7FFFu + ((v.u >> 16) & 1u)) >> 16);
}
__device__ __forceinline__ float bf2f(ushort u) {
  union { uint32_t u; float f; } v; v.u = (uint32_t)u << 16; return v.f;
}

__device__ __forceinline__ void gload_lds16(const void* g, void* l) {
  __builtin_amdgcn_global_load_lds(
      (const __attribute__((address_space(1))) void*)g,
      (__attribute__((address_space(3))) void*)l, 16, 0, 0);
}

__device__ __forceinline__ void wait_vm16() { asm volatile("s_waitcnt vmcnt(16)" ::: "memory"); }
__device__ __forceinline__ void wait_vm8()  { asm volatile("s_waitcnt vmcnt(8)"  ::: "memory"); }
__device__ __forceinline__ void wait_vm0()  { asm volatile("s_waitcnt vmcnt(0)"  ::: "memory"); }
__device__ __forceinline__ void wait_lgkm0(){ asm volatile("s_waitcnt lgkmcnt(0)" ::: "memory"); }
__device__ __forceinline__ void barrier_raw(){ asm volatile("s_barrier" ::: "memory"); }

template <int NN>
__device__ __forceinline__ void wht_inreg(float* v) {
#pragma unroll
  for (int h = 1; h < NN; h <<= 1)
#pragma unroll
    for (int g = 0; g < NN; g += (h << 1))
#pragma unroll
      for (int k = 0; k < h; ++k) {
        float a = v[g + k], b = v[g + k + h];
        v[g + k] = a + b; v[g + k + h] = a - b;
      }
}

// ---------------- prep roles: [0,2048) cvt x; [2048,10240) cvt W1_0;
// [10240,18432) cvt W2_0; 18432-3 make t; 18434-5 bias fastfood.
__global__ __launch_bounds__(256) void prep(
    const float4* __restrict__ x4, ushort4* __restrict__ xb4,
    const float4* __restrict__ W10, ushort4* __restrict__ W1b4,
    const float4* __restrict__ W20, ushort4* __restrict__ W2b4,
    const float* __restrict__ V,
    const float* __restrict__ BBW1, const float* __restrict__ BBW2,
    float* __restrict__ t1, float* __restrict__ t2,
    const float* __restrict__ BBb1, const int* __restrict__ Pib1,
    const float* __restrict__ GGb1, const float* __restrict__ b10,
    const float* __restrict__ BBb2, const int* __restrict__ Pib2,
    const float* __restrict__ GGb2, const float* __restrict__ b20,
    float* __restrict__ ob1, float* __restrict__ ob2) {
  __shared__ float ts[1024];
  __shared__ float zs[4096];
  __shared__ float red[4];
  const int bid = blockIdx.x;
  const int tid = threadIdx.x;

  if (bid < 18432) {                      // streaming f32->bf16 cvt
    const float4* src; ushort4* dst; int i;
    if (bid < 2048)       { src = x4;  dst = xb4;  i = bid * 256 + tid; }
    else if (bid < 10240) { src = W10; dst = W1b4; i = (bid - 2048) * 256 + tid; }
    else                  { src = W20; dst = W2b4; i = (bid - 10240) * 256 + tid; }
    float4 v = src[i];
    ushort4 o;
    o.x = f2bf(v.x); o.y = f2bf(v.y); o.z = f2bf(v.z); o.w = f2bf(v.w);
    dst[i] = o;
    return;
  }

  if (bid < 18434) {                      // make t
    const int which = bid - 18432;
    const float* BB = which ? BBW2 : BBW1;
    float* t = which ? t2 : t1;
    for (int i = tid; i < 1024; i += 256) ts[i] = BB[i] * V[i];
    for (int st = 0; st < 10; ++st) {
      int half = 1 << st;
      __syncthreads();
      for (int j = tid; j < 512; j += 256) {
        int p = ((j >> st) << (st + 1)) | (j & (half - 1));
        float a = ts[p], b = ts[p + half];
        ts[p] = a + b; ts[p + half] = a - b;
      }
    }
    __syncthreads();
    for (int i = tid; i < 1024; i += 256) t[i] = ts[i];
    return;
  }

  {                                       // bias fastfood
    const int which = bid - 18434;
    const int L = which ? 2048 : 4096;
    const float* BB = which ? BBb2 : BBb1;
    const int* Pi = which ? Pib2 : Pib1;
    const float* GG = which ? GGb2 : GGb1;
    const float* b0 = which ? b20 : b10;
    float* ob = which ? ob2 : ob1;

    for (int i = tid; i < 1024; i += 256) ts[i] = BB[i] * V[i];
    for (int st = 0; st < 10; ++st) {
      int half = 1 << st;
      __syncthreads();
      for (int j = tid; j < 512; j += 256) {
        int p = ((j >> st) << (st + 1)) | (j & (half - 1));
        float a = ts[p], b = ts[p + half];
        ts[p] = a + b; ts[p + half] = a - b;
      }
    }
    __syncthreads();
    float gsum = 0.f;
    for (int i = tid; i < L; i += 256) {
      int pi = Pi[i];
      float g = GG[i];
      gsum += g * g;
      zs[i] = ts[pi & 1023] * g;
    }
    for (int o = 32; o > 0; o >>= 1) gsum += __shfl_down(gsum, o);
    if ((tid & 63) == 0) red[tid >> 6] = gsum;
    __syncthreads();
    float ssum = red[0] + red[1] + red[2] + red[3];
    for (int st = 0; (1 << st) < L; ++st) {
      int half = 1 << st;
      __syncthreads();
      for (int j = tid; j < (L >> 1); j += 256) {
        int p = ((j >> st) << (st + 1)) | (j & (half - 1));
        float a = zs[p], b = zs[p + half];
        zs[p] = a + b; zs[p + half] = a - b;
      }
    }
    __syncthreads();
    float scale = rsqrtf((float)L * ssum);
    for (int i = tid; i < L; i += 256) ob[i] = b0[i] + zs[i] * scale;
  }
}

// ---------------- build_z (one weight): Z = bf16(t[Pi&1023]*GG) + sum(G^2).
// CRITICAL FIX vs r7: the ts barrier comes BEFORE the Pi/GG loads, so the
// stream is never drained by a barrier — only counted per-use vmcnt waits.
__global__ __launch_bounds__(256) void build_z(
    const int* __restrict__ Pi, const float* __restrict__ GG,
    const float* __restrict__ t, ushort* __restrict__ z,
    float* __restrict__ partials) {
  __shared__ float ts[1024];
  __shared__ float red[4];
  const int tid = threadIdx.x;
  const size_t base = (size_t)blockIdx.x << 13;

  for (int i = tid; i < 1024; i += 256) ts[i] = t[i];
  __syncthreads();                        // only ts loads drained here

  const int4* Pi4 = (const int4*)(Pi + base);
  const float4* GG4 = (const float4*)(GG + base);
  float gsum = 0.f;
#pragma unroll
  for (int q = 0; q < 4; ++q) {
    const int4 pa = Pi4[(q << 9) + (tid << 1)];
    const int4 pb = Pi4[(q << 9) + (tid << 1) + 1];
    const float4 ga = GG4[(q << 9) + (tid << 1)];
    const float4 gb = GG4[(q << 9) + (tid << 1) + 1];
    gsum += ga.x * ga.x + ga.y * ga.y + ga.z * ga.z + ga.w * ga.w
          + gb.x * gb.x + gb.y * gb.y + gb.z * gb.z + gb.w * gb.w;
    short8 o;
    o[0] = (short)f2bf(ts[pa.x & 1023] * ga.x);
    o[1] = (short)f2bf(ts[pa.y & 1023] * ga.y);
    o[2] = (short)f2bf(ts[pa.z & 1023] * ga.z);
    o[3] = (short)f2bf(ts[pa.w & 1023] * ga.w);
    o[4] = (short)f2bf(ts[pb.x & 1023] * gb.x);
    o[5] = (short)f2bf(ts[pb.y & 1023] * gb.y);
    o[6] = (short)f2bf(ts[pb.z & 1023] * gb.z);
    o[7] = (short)f2bf(ts[pb.w & 1023] * gb.w);
    *(short8*)(z + base + (q << 11) + (tid << 3)) = o;
  }
  for (int o2 = 32; o2 > 0; o2 >>= 1) gsum += __shfl_down(gsum, o2);
  if ((tid & 63) == 0) red[tid >> 6] = gsum;
  __syncthreads();
  if (tid == 0) partials[blockIdx.x] = red[0] + red[1] + red[2] + red[3];
}

// ---------------- rowwht2048: per-row 2048-pt WHT. 8 rows/block, 32 thr/row.
// Phase A: radix-64 on contiguous elems [64k,64k+64) in registers.
// Phase B: radix-32 over stride-64 (two residues 2k,2k+1 per thread).
// LDS bf16, skew phys(i)=i+4*(i>>6) (reads 2-way / writes 2-way = free).
template <bool IN_F32, bool OUT_F32, bool SCALE>
__global__ __launch_bounds__(256) void rowwht2048(
    const void* __restrict__ in, void* __restrict__ outp,
    const float* __restrict__ partials) {
  __shared__ ushort tile[8][2176];
  __shared__ float red[4];
  const int tid = threadIdx.x;
  const int r = tid >> 5;
  const int k = tid & 31;
  const int row = (blockIdx.x << 3) + r;
  if constexpr (SCALE) {
    float s = partials[tid] + partials[tid + 256] + partials[tid + 512] + partials[tid + 768];
    for (int o = 32; o > 0; o >>= 1) s += __shfl_down(s, o);
    if ((tid & 63) == 0) red[tid >> 6] = s;
  }
  float v[64];
  if constexpr (IN_F32) {
    const float4* ip = (const float4*)((const float*)in + ((size_t)row << 11) + (k << 6));
#pragma unroll
    for (int j = 0; j < 16; ++j) {
      float4 d = ip[j];
      v[4 * j] = d.x; v[4 * j + 1] = d.y; v[4 * j + 2] = d.z; v[4 * j + 3] = d.w;
    }
  } else {
    const ushort* ip = (const ushort*)in + ((size_t)row << 11) + (k << 6);
#pragma unroll
    for (int j = 0; j < 8; ++j) {
      short8 d = *(const short8*)(ip + (j << 3));
#pragma unroll
      for (int e = 0; e < 8; ++e) v[8 * j + e] = bf2f((ushort)d[e]);
    }
  }
  wht_inreg<64>(v);
  {
    ushort* tp = &tile[r][68 * k];
#pragma unroll
    for (int j = 0; j < 16; ++j) {
      ushort4 u;
      u.x = f2bf(v[4 * j]); u.y = f2bf(v[4 * j + 1]);
      u.z = f2bf(v[4 * j + 2]); u.w = f2bf(v[4 * j + 3]);
      *(ushort4*)(tp + (j << 2)) = u;
    }
  }
  __syncthreads();
  float sc = 1.f;
  if constexpr (SCALE) sc = rsqrtf(8388608.f * (red[0] + red[1] + red[2] + red[3]));

  float va[32], vb[32];
#pragma unroll
  for (int m = 0; m < 32; ++m) {
    ushort2 u = *(const ushort2*)&tile[r][(k << 1) + 68 * m];
    va[m] = bf2f(u.x); vb[m] = bf2f(u.y);
  }
  wht_inreg<32>(va); wht_inreg<32>(vb);
  if constexpr (OUT_F32) {
    float* op = (float*)outp + ((size_t)row << 11) + (k << 1);
#pragma unroll
    for (int m = 0; m < 32; ++m) {
      float2 o; o.x = va[m] * sc; o.y = vb[m] * sc;
      *(float2*)(op + (m << 6)) = o;
    }
  } else {
    ushort* op = (ushort*)outp + ((size_t)row << 11) + (k << 1);
#pragma unroll
    for (int m = 0; m < 32; ++m) {
      ushort2 o; o.x = f2bf(va[m] * sc); o.y = f2bf(vb[m] * sc);
      *(ushort2*)(op + (m << 6)) = o;
    }
  }
}

// ---------------- rowwht4096: per-row 4096-pt WHT. 4 rows/block, 64 thr/row.
// Phase A radix-64 contiguous; Phase B radix-64 stride-64. Safe in-place.
template <bool SCALE>
__global__ __launch_bounds__(256) void rowwht4096(
    const ushort* __restrict__ in, ushort* __restrict__ outp,
    const float* __restrict__ partials) {
  __shared__ ushort tile[4][4352];
  __shared__ float red[4];
  const int tid = threadIdx.x;
  const int r = tid >> 6;
  const int k = tid & 63;
  const int row = (blockIdx.x << 2) + r;
  if constexpr (SCALE) {
    float s = partials[tid] + partials[tid + 256] + partials[tid + 512] + partials[tid + 768];
    for (int o = 32; o > 0; o >>= 1) s += __shfl_down(s, o);
    if ((tid & 63) == 0) red[tid >> 6] = s;
  }
  float v[64];
  const ushort* ip = in + ((size_t)row << 12) + (k << 6);
#pragma unroll
  for (int j = 0; j < 8; ++j) {
    short8 d = *(const short8*)(ip + (j << 3));
#pragma unroll
    for (int e = 0; e < 8; ++e) v[8 * j + e] = bf2f((ushort)d[e]);
  }
  wht_inreg<64>(v);
  {
    ushort* tp = &tile[r][68 * k];
#pragma unroll
    for (int j = 0; j < 16; ++j) {
      ushort4 u;
      u.x = f2bf(v[4 * j]); u.y = f2bf(v[4 * j + 1]);
      u.z = f2bf(v[4 * j + 2]); u.w = f2bf(v[4 * j + 3]);
      *(ushort4*)(tp + (j << 2)) = u;
    }
  }
  __syncthreads();
  float sc = 1.f;
  if constexpr (SCALE) sc = rsqrtf(8388608.f * (red[0] + red[1] + red[2] + red[3]));

  float w[64];
#pragma unroll
  for (int m = 0; m < 64; ++m) w[m] = bf2f(tile[r][k + 68 * m]);
  wht_inreg<64>(w);
  ushort* op = outp + ((size_t)row << 12) + k;
#pragma unroll
  for (int m = 0; m < 64; ++m) op[m << 6] = f2bf(w[m] * sc);
}

// ---------------- C = A * B^T  (A: MxK bf16, B: NxK bf16, row-major).
// 128x128 tile, BK=64, 4 waves, 4-buffer LDS pipeline, counted vmcnt,
// both-sides XOR swizzle. EPI: 2 = bf16(acc); 3 = bf16(relu(acc+bias+Waux));
// 4 = f32 acc+bias+Waux -> Cf.
template <int EPI, int NT>
__global__ __launch_bounds__(256) void gemm_bt(
    const ushort* __restrict__ A, const ushort* __restrict__ B,
    const float* __restrict__ bias, const ushort* __restrict__ Waux,
    ushort* __restrict__ Cb, float* __restrict__ Cf,
    int M, int N, int K) {
  __shared__ ushort As[4][8192];
  __shared__ ushort Bs[4][8192];
  const int tid = threadIdx.x;
  const int w = tid >> 6, l = tid & 63;
  const int wr = w >> 1, wc = w & 1;
  const int brow = blockIdx.y << 7, bcol = blockIdx.x << 7;
  const int lrow = l >> 3;
  const int csrc = ((l & 7) ^ lrow) << 3;
  const int l15 = l & 15;
  const int x7 = l15 & 7;
  f32x4 acc[4][4] = {};

  const ushort* pa = A + (size_t)(brow + (w << 5) + lrow) * K + csrc;
  const ushort* pb = B + (size_t)(bcol + (w << 5) + lrow) * K + csrc;
  const size_t K8 = (size_t)K << 3;

#define STAGE(buf, tt)                                                      \
  {                                                                         \
    const ushort* qa = pa + ((tt) << 6);                                    \
    const ushort* qb = pb + ((tt) << 6);                                    \
    _Pragma("unroll")                                                       \
    for (int i = 0; i < 4; ++i) {                                           \
      gload_lds16(qa + K8 * i, &As[buf][(((w << 2) + i) << 9)]);            \
      gload_lds16(qb + K8 * i, &Bs[buf][(((w << 2) + i) << 9)]);            \
    }                                                                       \
  }

  STAGE(0, 0); STAGE(1, 1); STAGE(2, 2);
  for (int t = 0; t < NT; ++t) {
    if (t < NT - 2) wait_vm16();
    else if (t == NT - 2) wait_vm8();
    else wait_vm0();
    barrier_raw();
    if (t + 3 < NT) STAGE((t + 3) & 3, t + 3);
    const ushort* Acur = As[t & 3];
    const ushort* Bcur = Bs[t & 3];
    bf16x8 af[2][4], bfr[2][4];
#pragma unroll
    for (int kk = 0; kk < 2; ++kk) {
      int c8 = (kk << 2) + (l >> 4);
#pragma unroll
      for (int m = 0; m < 4; ++m)
        af[kk][m] = *(const bf16x8*)&Acur[(((wr << 6) + (m << 4) + l15) << 6) + ((c8 ^ x7) << 3)];
#pragma unroll
      for (int n = 0; n < 4; ++n)
        bfr[kk][n] = *(const bf16x8*)&Bcur[(((wc << 6) + (n << 4) + l15) << 6) + ((c8 ^ x7) << 3)];
    }
    wait_lgkm0();
#pragma unroll
    for (int kk = 0; kk < 2; ++kk)
#pragma unroll
      for (int m = 0; m < 4; ++m)
#pragma unroll
        for (int n = 0; n < 4; ++n)
          acc[m][n] = __builtin_amdgcn_mfma_f32_16x16x32_bf16(af[kk][m], bfr[kk][n], acc[m][n], 0, 0, 0);
  }
#undef STAGE

#pragma unroll
  for (int n = 0; n < 4; ++n) {
    int col = bcol + (wc << 6) + (n << 4) + l15;
    float bv = (EPI == 2) ? 0.f : bias[col];
#pragma unroll
    for (int m = 0; m < 4; ++m) {
      int row0 = brow + (wr << 6) + (m << 4) + ((l >> 4) << 2);
#pragma unroll
      for (int j = 0; j < 4; ++j) {
        size_t idx = (size_t)(row0 + j) * N + col;
        if (EPI == 2) {
          Cb[idx] = f2bf(acc[m][n][j]);
        } else if (EPI == 3) {
          float vv = acc[m][n][j] + bv + bf2f(Waux[idx]);
          Cb[idx] = f2bf(fmaxf(vv, 0.f));
        } else {
          Cf[idx] = acc[m][n][j] + bv + bf2f(Waux[idx]);
        }
      }
    }
  }
}

extern "C" void kernel_launch(void* const* d_in, const int* in_sizes, int n_in,
                              void* d_out, int out_size, void* d_ws, size_t ws_size,
                              hipStream_t stream) {
  const float* x     = (const float*)d_in[0];
  const float* V     = (const float*)d_in[1];
  const float* W1_0  = (const float*)d_in[2];
  const float* b1_0  = (const float*)d_in[3];
  const float* W2_0  = (const float*)d_in[4];
  const float* b2_0  = (const float*)d_in[5];
  const float* BB_W1 = (const float*)d_in[6];
  const int*   Pi_W1 = (const int*)d_in[7];
  const float* GG_W1 = (const float*)d_in[8];
  const float* BB_b1 = (const float*)d_in[9];
  const int*   Pi_b1 = (const int*)d_in[10];
  const float* GG_b1 = (const float*)d_in[11];
  const float* BB_W2 = (const float*)d_in[12];
  const int*   Pi_W2 = (const int*)d_in[13];
  const float* GG_W2 = (const float*)d_in[14];
  const float* BB_b2 = (const float*)d_in[15];
  const int*   Pi_b2 = (const int*)d_in[16];
  const float* GG_b2 = (const float*)d_in[17];
  float* out = (float*)d_out;

  const size_t MB = 1048576ull;
  char* ws = (char*)d_ws;
  // Slots (72 MB + 40 KB total; lifetimes disjoint per dispatch order below):
  ushort* W2b = (ushort*)(ws);                 // 0-16   (d1 .. d11)
  ushort* W1b = (ushort*)(ws + 16 * MB);       // 16-32  (d1 .. d6)
  ushort* hH  = (ushort*)(ws + 16 * MB);       //   16-24 (d8 .. d9)
  ushort* w2  = (ushort*)(ws + 24 * MB);       //   24-28 (d10.. d11)
  ushort* Y   = (ushort*)(ws + 32 * MB);       // 32-48  Y1 (d3..d4), Y2 (d7..d9)
  ushort* hb  = (ushort*)(ws + 48 * MB);       // 48-56  (d6 .. d11)
  ushort* v1b = (ushort*)(ws + 56 * MB);       // 56-64  v1 (d4..d5) -> w1 in-place (d5..d6)
  ushort* xb  = (ushort*)(ws + 64 * MB);       // 64-68  (d1 .. d6)
  ushort* ub  = (ushort*)(ws + 68 * MB);       // 68-72  u (d2..d4) -> v2b (d9..d10)
  char*   S   = ws + 72 * MB;
  float* t1     = (float*)(S);
  float* t2     = (float*)(S + 4096);
  float* b1     = (float*)(S + 8192);
  float* b2     = (float*)(S + 8192 + 16384);
  float* parts1 = (float*)(S + 8192 + 16384 + 8192);
  float* parts2 = (float*)(S + 8192 + 16384 + 8192 + 4096);
  ushort* w1  = v1b;
  ushort* v2b = ub;

  // d1: cvt x/W1_0/W2_0 -> bf16, t1/t2, bias fastfoods
  prep<<<18436, 256, 0, stream>>>((const float4*)x, (ushort4*)xb,
                                  (const float4*)W1_0, (ushort4*)W1b,
                                  (const float4*)W2_0, (ushort4*)W2b,
                                  V, BB_W1, BB_W2, t1, t2,
                                  BB_b1, Pi_b1, GG_b1, b1_0,
                                  BB_b2, Pi_b2, GG_b2, b2_0, b1, b2);
  // d2: u = rowWHT_2048(x)
  rowwht2048<true, false, false><<<128, 256, 0, stream>>>(x, ub, nullptr);
  // d3: Y1 = gather(Pi_W1, GG_W1)
  build_z<<<1024, 256, 0, stream>>>(Pi_W1, GG_W1, t1, Y, parts1);
  // d4: v1 = u @ Y1^T
  gemm_bt<2, 32><<<dim3(32, 8), 256, 0, stream>>>(ub, Y, nullptr, nullptr, v1b, nullptr, 1024, 4096, 2048);
  // d5: w1 = sc1 * rowWHT_4096(v1)   (in-place)
  rowwht4096<true><<<256, 256, 0, stream>>>(v1b, w1, parts1);
  // d6: h = relu(x@W1b^T + w1 + b1)
  gemm_bt<3, 32><<<dim3(32, 8), 256, 0, stream>>>(xb, W1b, b1, w1, hb, nullptr, 1024, 4096, 2048);
  // d7: Y2 = gather(Pi_W2, GG_W2)
  build_z<<<1024, 256, 0, stream>>>(Pi_W2, GG_W2, t2, Y, parts2);
  // d8: hH = rowWHT_4096(h)
  rowwht4096<false><<<256, 256, 0, stream>>>(hb, hH, nullptr);
  // d9: v2 = hH @ Y2^T
  gemm_bt<2, 64><<<dim3(16, 8), 256, 0, stream>>>(hH, Y, nullptr, nullptr, v2b, nullptr, 1024, 2048, 4096);
  // d10: w2 = sc2 * rowWHT_2048(v2)
  rowwht2048<false, false, true><<<128, 256, 0, stream>>>(v2b, w2, parts2);
  // d11: out = h@W2b^T + w2 + b2   (f32)
  gemm_bt<4, 64><<<dim3(16, 8), 256, 0, stream>>>(hb, W2b, b2, w2, nullptr, out, 1024, 2048, 4096);
}

// Round 10
// 238.554 us; speedup vs baseline: 1.2167x; 1.2167x over previous
//
#include <hip/hip_runtime.h>
#include <hip/hip_bf16.h>
#include <stdint.h>

// B=1024, D_IN=2048, D_H=4096, D_OUT=2048, D_INT=1024
// Algebra: W_ff = H_R Z H_C, Z = gather(t,Pi,GG).reshape(R,C).
// x@W_ff^T = rowWHT_R( (rowWHT_C(x)) @ Z^T ) * sc  — WHTs act on activations.

typedef __attribute__((ext_vector_type(8))) short bf16x8;
typedef __attribute__((ext_vector_type(8))) short short8;
typedef __attribute__((ext_vector_type(4))) float f32x4;

__device__ __forceinline__ ushort f2bf(float f) {
  union { float f; uint32_t u; } v; v.f = f;
  return (ushort)((v.u + 0x7FFFu + ((v.u >> 16) & 1u)) >> 16);
}
__device__ __forceinline__ float bf2f(ushort u) {
  union { uint32_t u; float f; } v; v.u = (uint32_t)u << 16; return v.f;
}

__device__ __forceinline__ void gload_lds16(const void* g, void* l) {
  __builtin_amdgcn_global_load_lds(
      (const __attribute__((address_space(1))) void*)g,
      (__attribute__((address_space(3))) void*)l, 16, 0, 0);
}

__device__ __forceinline__ void wait_vm8()  { asm volatile("s_waitcnt vmcnt(8)"  ::: "memory"); }
__device__ __forceinline__ void wait_vm4()  { asm volatile("s_waitcnt vmcnt(4)"  ::: "memory"); }
__device__ __forceinline__ void wait_vm0()  { asm volatile("s_waitcnt vmcnt(0)"  ::: "memory"); }
__device__ __forceinline__ void wait_lgkm0(){ asm volatile("s_waitcnt lgkmcnt(0)" ::: "memory"); }
__device__ __forceinline__ void barrier_raw(){ asm volatile("s_barrier" ::: "memory"); }

template <int NN>
__device__ __forceinline__ void wht_inreg(float* v) {
#pragma unroll
  for (int h = 1; h < NN; h <<= 1)
#pragma unroll
    for (int g = 0; g < NN; g += (h << 1))
#pragma unroll
      for (int k = 0; k < h; ++k) {
        float a = v[g + k], b = v[g + k + h];
        v[g + k] = a + b; v[g + k + h] = a - b;
      }
}

// ---------------- prep: [0,2048) cvt x; [2048,10240) cvt W1_0; [10240,18432)
// cvt W2_0; 18432-3 make t; 18434-5 bias fastfood.  [r9-proven]
__global__ __launch_bounds__(256) void prep(
    const float4* __restrict__ x4, ushort4* __restrict__ xb4,
    const float4* __restrict__ W10, ushort4* __restrict__ W1b4,
    const float4* __restrict__ W20, ushort4* __restrict__ W2b4,
    const float* __restrict__ V,
    const float* __restrict__ BBW1, const float* __restrict__ BBW2,
    float* __restrict__ t1, float* __restrict__ t2,
    const float* __restrict__ BBb1, const int* __restrict__ Pib1,
    const float* __restrict__ GGb1, const float* __restrict__ b10,
    const float* __restrict__ BBb2, const int* __restrict__ Pib2,
    const float* __restrict__ GGb2, const float* __restrict__ b20,
    float* __restrict__ ob1, float* __restrict__ ob2) {
  __shared__ float ts[1024];
  __shared__ float zs[4096];
  __shared__ float red[4];
  const int bid = blockIdx.x;
  const int tid = threadIdx.x;

  if (bid < 18432) {
    const float4* src; ushort4* dst; int i;
    if (bid < 2048)       { src = x4;  dst = xb4;  i = bid * 256 + tid; }
    else if (bid < 10240) { src = W10; dst = W1b4; i = (bid - 2048) * 256 + tid; }
    else                  { src = W20; dst = W2b4; i = (bid - 10240) * 256 + tid; }
    float4 v = src[i];
    ushort4 o;
    o.x = f2bf(v.x); o.y = f2bf(v.y); o.z = f2bf(v.z); o.w = f2bf(v.w);
    dst[i] = o;
    return;
  }

  if (bid < 18434) {
    const int which = bid - 18432;
    const float* BB = which ? BBW2 : BBW1;
    float* t = which ? t2 : t1;
    for (int i = tid; i < 1024; i += 256) ts[i] = BB[i] * V[i];
    for (int st = 0; st < 10; ++st) {
      int half = 1 << st;
      __syncthreads();
      for (int j = tid; j < 512; j += 256) {
        int p = ((j >> st) << (st + 1)) | (j & (half - 1));
        float a = ts[p], b = ts[p + half];
        ts[p] = a + b; ts[p + half] = a - b;
      }
    }
    __syncthreads();
    for (int i = tid; i < 1024; i += 256) t[i] = ts[i];
    return;
  }

  {
    const int which = bid - 18434;
    const int L = which ? 2048 : 4096;
    const float* BB = which ? BBb2 : BBb1;
    const int* Pi = which ? Pib2 : Pib1;
    const float* GG = which ? GGb2 : GGb1;
    const float* b0 = which ? b20 : b10;
    float* ob = which ? ob2 : ob1;

    for (int i = tid; i < 1024; i += 256) ts[i] = BB[i] * V[i];
    for (int st = 0; st < 10; ++st) {
      int half = 1 << st;
      __syncthreads();
      for (int j = tid; j < 512; j += 256) {
        int p = ((j >> st) << (st + 1)) | (j & (half - 1));
        float a = ts[p], b = ts[p + half];
        ts[p] = a + b; ts[p + half] = a - b;
      }
    }
    __syncthreads();
    float gsum = 0.f;
    for (int i = tid; i < L; i += 256) {
      int pi = Pi[i];
      float g = GG[i];
      gsum += g * g;
      zs[i] = ts[pi & 1023] * g;
    }
    for (int o = 32; o > 0; o >>= 1) gsum += __shfl_down(gsum, o);
    if ((tid & 63) == 0) red[tid >> 6] = gsum;
    __syncthreads();
    float ssum = red[0] + red[1] + red[2] + red[3];
    for (int st = 0; (1 << st) < L; ++st) {
      int half = 1 << st;
      __syncthreads();
      for (int j = tid; j < (L >> 1); j += 256) {
        int p = ((j >> st) << (st + 1)) | (j & (half - 1));
        float a = zs[p], b = zs[p + half];
        zs[p] = a + b; zs[p + half] = a - b;
      }
    }
    __syncthreads();
    float scale = rsqrtf((float)L * ssum);
    for (int i = tid; i < L; i += 256) ob[i] = b0[i] + zs[i] * scale;
  }
}

// ---------------- build_z: Z = bf16(t[Pi&1023]*GG) + per-block sum(G^2). [r9-proven]
__global__ __launch_bounds__(256) void build_z(
    const int* __restrict__ Pi, const float* __restrict__ GG,
    const float* __restrict__ t, ushort* __restrict__ z,
    float* __restrict__ partials) {
  __shared__ float ts[1024];
  __shared__ float red[4];
  const int tid = threadIdx.x;
  const size_t base = (size_t)blockIdx.x << 13;

  for (int i = tid; i < 1024; i += 256) ts[i] = t[i];
  __syncthreads();

  const int4* Pi4 = (const int4*)(Pi + base);
  const float4* GG4 = (const float4*)(GG + base);
  float gsum = 0.f;
#pragma unroll
  for (int q = 0; q < 4; ++q) {
    const int4 pa = Pi4[(q << 9) + (tid << 1)];
    const int4 pb = Pi4[(q << 9) + (tid << 1) + 1];
    const float4 ga = GG4[(q << 9) + (tid << 1)];
    const float4 gb = GG4[(q << 9) + (tid << 1) + 1];
    gsum += ga.x * ga.x + ga.y * ga.y + ga.z * ga.z + ga.w * ga.w
          + gb.x * gb.x + gb.y * gb.y + gb.z * gb.z + gb.w * gb.w;
    short8 o;
    o[0] = (short)f2bf(ts[pa.x & 1023] * ga.x);
    o[1] = (short)f2bf(ts[pa.y & 1023] * ga.y);
    o[2] = (short)f2bf(ts[pa.z & 1023] * ga.z);
    o[3] = (short)f2bf(ts[pa.w & 1023] * ga.w);
    o[4] = (short)f2bf(ts[pb.x & 1023] * gb.x);
    o[5] = (short)f2bf(ts[pb.y & 1023] * gb.y);
    o[6] = (short)f2bf(ts[pb.z & 1023] * gb.z);
    o[7] = (short)f2bf(ts[pb.w & 1023] * gb.w);
    *(short8*)(z + base + (q << 11) + (tid << 3)) = o;
  }
  for (int o2 = 32; o2 > 0; o2 >>= 1) gsum += __shfl_down(gsum, o2);
  if ((tid & 63) == 0) red[tid >> 6] = gsum;
  __syncthreads();
  if (tid == 0) partials[blockIdx.x] = red[0] + red[1] + red[2] + red[3];
}

// ---------------- rowwht2048: per-row 2048-pt WHT, 8 rows/block, 32 thr/row.
// INMODE 0: f32 input; INMODE 2: sum of two f32 planes. Output bf16.
template <int INMODE, bool SCALE>
__global__ __launch_bounds__(256) void rowwht2048(
    const float* __restrict__ in0, const float* __restrict__ in1,
    ushort* __restrict__ outp, const float* __restrict__ partials) {
  __shared__ ushort tile[8][2176];
  __shared__ float red[4];
  const int tid = threadIdx.x;
  const int r = tid >> 5;
  const int k = tid & 31;
  const int row = (blockIdx.x << 3) + r;
  if constexpr (SCALE) {
    float s = partials[tid] + partials[tid + 256] + partials[tid + 512] + partials[tid + 768];
    for (int o = 32; o > 0; o >>= 1) s += __shfl_down(s, o);
    if ((tid & 63) == 0) red[tid >> 6] = s;
  }
  float v[64];
  {
    const float4* ip = (const float4*)(in0 + ((size_t)row << 11) + (k << 6));
#pragma unroll
    for (int j = 0; j < 16; ++j) {
      float4 d = ip[j];
      v[4 * j] = d.x; v[4 * j + 1] = d.y; v[4 * j + 2] = d.z; v[4 * j + 3] = d.w;
    }
    if constexpr (INMODE == 2) {
      const float4* iq = (const float4*)(in1 + ((size_t)row << 11) + (k << 6));
#pragma unroll
      for (int j = 0; j < 16; ++j) {
        float4 d = iq[j];
        v[4 * j] += d.x; v[4 * j + 1] += d.y; v[4 * j + 2] += d.z; v[4 * j + 3] += d.w;
      }
    }
  }
  wht_inreg<64>(v);
  {
    ushort* tp = &tile[r][68 * k];
#pragma unroll
    for (int j = 0; j < 16; ++j) {
      ushort4 u;
      u.x = f2bf(v[4 * j]); u.y = f2bf(v[4 * j + 1]);
      u.z = f2bf(v[4 * j + 2]); u.w = f2bf(v[4 * j + 3]);
      *(ushort4*)(tp + (j << 2)) = u;
    }
  }
  __syncthreads();
  float sc = 1.f;
  if constexpr (SCALE) sc = rsqrtf(8388608.f * (red[0] + red[1] + red[2] + red[3]));

  float va[32], vb[32];
#pragma unroll
  for (int m = 0; m < 32; ++m) {
    ushort2 u = *(const ushort2*)&tile[r][(k << 1) + 68 * m];
    va[m] = bf2f(u.x); vb[m] = bf2f(u.y);
  }
  wht_inreg<32>(va); wht_inreg<32>(vb);
  ushort* op = outp + ((size_t)row << 11) + (k << 1);
#pragma unroll
  for (int m = 0; m < 32; ++m) {
    ushort2 o; o.x = f2bf(va[m] * sc); o.y = f2bf(vb[m] * sc);
    *(ushort2*)(op + (m << 6)) = o;
  }
}

// ---------------- rowwht4096: per-row 4096-pt WHT, 4 rows/block. [r9-proven]
template <bool SCALE>
__global__ __launch_bounds__(256) void rowwht4096(
    const ushort* __restrict__ in, ushort* __restrict__ outp,
    const float* __restrict__ partials) {
  __shared__ ushort tile[4][4352];
  __shared__ float red[4];
  const int tid = threadIdx.x;
  const int r = tid >> 6;
  const int k = tid & 63;
  const int row = (blockIdx.x << 2) + r;
  if constexpr (SCALE) {
    float s = partials[tid] + partials[tid + 256] + partials[tid + 512] + partials[tid + 768];
    for (int o = 32; o > 0; o >>= 1) s += __shfl_down(s, o);
    if ((tid & 63) == 0) red[tid >> 6] = s;
  }
  float v[64];
  const ushort* ip = in + ((size_t)row << 12) + (k << 6);
#pragma unroll
  for (int j = 0; j < 8; ++j) {
    short8 d = *(const short8*)(ip + (j << 3));
#pragma unroll
    for (int e = 0; e < 8; ++e) v[8 * j + e] = bf2f((ushort)d[e]);
  }
  wht_inreg<64>(v);
  {
    ushort* tp = &tile[r][68 * k];
#pragma unroll
    for (int j = 0; j < 16; ++j) {
      ushort4 u;
      u.x = f2bf(v[4 * j]); u.y = f2bf(v[4 * j + 1]);
      u.z = f2bf(v[4 * j + 2]); u.w = f2bf(v[4 * j + 3]);
      *(ushort4*)(tp + (j << 2)) = u;
    }
  }
  __syncthreads();
  float sc = 1.f;
  if constexpr (SCALE) sc = rsqrtf(8388608.f * (red[0] + red[1] + red[2] + red[3]));

  float w[64];
#pragma unroll
  for (int m = 0; m < 64; ++m) w[m] = bf2f(tile[r][k + 68 * m]);
  wht_inreg<64>(w);
  ushort* op = outp + ((size_t)row << 12) + k;
#pragma unroll
  for (int m = 0; m < 64; ++m) op[m << 6] = f2bf(w[m] * sc);
}

// ---------------- gemm8: C = A*B^T, 128x128 tile, BK=64, **8 waves** (2x4,
// each wave 64x32 out) -> 2 waves/SIMD so vmcnt/barrier stalls of one wave are
// covered by the other's MFMAs. 4-buffer LDS (128 KB), 3-deep prefetch,
// counted vmcnt, raw s_barrier, both-sides XOR swizzle.
// EPI 1: f32 acc -> plane (Cf0/Cf1 by blockIdx.z); EPI 2: bf16(acc);
// EPI 3: bf16(relu(acc + bias + Waux)).
template <int EPI, int NT>
__global__ __launch_bounds__(512) void gemm8(
    const ushort* __restrict__ A, const ushort* __restrict__ B,
    const float* __restrict__ bias, const ushort* __restrict__ Waux,
    ushort* __restrict__ Cb, float* __restrict__ Cf0, float* __restrict__ Cf1,
    int M, int N, int K) {
  __shared__ ushort As[4][8192];
  __shared__ ushort Bs[4][8192];
  const int tid = threadIdx.x;
  const int w = tid >> 6, l = tid & 63;
  const int wr = w >> 2, wc = w & 3;          // 2x4 wave grid
  const int brow = blockIdx.y << 7, bcol = blockIdx.x << 7;
  const int srow = tid >> 3;                  // staging row 0..63
  const int sg = tid & 7;                     // granule 0..7
  const int csrc = (sg ^ (srow & 7)) << 3;    // swizzled src col (ushort)
  const int l15 = l & 15;
  const int kb = blockIdx.z * (NT << 6);
  f32x4 acc[4][2] = {};

  const ushort* pa0 = A + (size_t)(brow + srow) * K + kb + csrc;
  const ushort* pb0 = B + (size_t)(bcol + srow) * K + kb + csrc;
  const size_t K64 = (size_t)K << 6;          // 64 rows stride (ushorts)

#define STAGE(buf, tt)                                                \
  {                                                                   \
    const ushort* qa = pa0 + ((tt) << 6);                             \
    const ushort* qb = pb0 + ((tt) << 6);                             \
    gload_lds16(qa,       (char*)As[buf] + (tid << 4));               \
    gload_lds16(qa + K64, (char*)As[buf] + (tid << 4) + 8192);        \
    gload_lds16(qb,       (char*)Bs[buf] + (tid << 4));               \
    gload_lds16(qb + K64, (char*)Bs[buf] + (tid << 4) + 8192);        \
  }

  STAGE(0, 0); STAGE(1, 1); STAGE(2, 2);      // 12 outstanding / thread-group
  for (int t = 0; t < NT; ++t) {
    if (t < NT - 2) wait_vm8();
    else if (t == NT - 2) wait_vm4();
    else wait_vm0();
    barrier_raw();
    if (t + 3 < NT) STAGE((t + 3) & 3, t + 3);
    const ushort* Acur = As[t & 3];
    const ushort* Bcur = Bs[t & 3];
    bf16x8 af[2][4], bfr[2][2];
#pragma unroll
    for (int kk = 0; kk < 2; ++kk) {
      int c8 = (kk << 2) + (l >> 4);
#pragma unroll
      for (int m = 0; m < 4; ++m) {
        int ra = (wr << 6) + (m << 4) + l15;
        af[kk][m] = *(const bf16x8*)&Acur[(ra << 6) + ((c8 ^ (ra & 7)) << 3)];
      }
#pragma unroll
      for (int n = 0; n < 2; ++n) {
        int rb = (wc << 5) + (n << 4) + l15;
        bfr[kk][n] = *(const bf16x8*)&Bcur[(rb << 6) + ((c8 ^ (rb & 7)) << 3)];
      }
    }
    wait_lgkm0();
#pragma unroll
    for (int kk = 0; kk < 2; ++kk)
#pragma unroll
      for (int m = 0; m < 4; ++m)
#pragma unroll
        for (int n = 0; n < 2; ++n)
          acc[m][n] = __builtin_amdgcn_mfma_f32_16x16x32_bf16(af[kk][m], bfr[kk][n], acc[m][n], 0, 0, 0);
  }
#undef STAGE

  float* outp = (EPI == 1) ? (blockIdx.z ? Cf1 : Cf0) : nullptr;
#pragma unroll
  for (int n = 0; n < 2; ++n) {
    int col = bcol + (wc << 5) + (n << 4) + l15;
    float bv = (EPI == 3) ? bias[col] : 0.f;
#pragma unroll
    for (int m = 0; m < 4; ++m) {
      int row0 = brow + (wr << 6) + (m << 4) + ((l >> 4) << 2);
#pragma unroll
      for (int j = 0; j < 4; ++j) {
        size_t idx = (size_t)(row0 + j) * N + col;
        if (EPI == 1) {
          outp[idx] = acc[m][n][j];
        } else if (EPI == 2) {
          Cb[idx] = f2bf(acc[m][n][j]);
        } else {
          float vv = acc[m][n][j] + bv + bf2f(Waux[idx]);
          Cb[idx] = f2bf(fmaxf(vv, 0.f));
        }
      }
    }
  }
}

// ---------------- out = PP0 + PP1 + w2(bf16) + b2   (1024x2048 f32)
__global__ __launch_bounds__(256) void reduce_out(
    const float4* __restrict__ PP0, const float4* __restrict__ PP1,
    const ushort4* __restrict__ w2, const float* __restrict__ b2,
    float4* __restrict__ out) {
  int i = blockIdx.x * 256 + threadIdx.x;     // 524288 f4
  float4 a = PP0[i], b = PP1[i];
  ushort4 wz = w2[i];
  const float4 bb = *(const float4*)(b2 + ((i & 511) << 2));
  float4 o;
  o.x = a.x + b.x + bf2f(wz.x) + bb.x;
  o.y = a.y + b.y + bf2f(wz.y) + bb.y;
  o.z = a.z + b.z + bf2f(wz.z) + bb.z;
  o.w = a.w + b.w + bf2f(wz.w) + bb.w;
  out[i] = o;
}

extern "C" void kernel_launch(void* const* d_in, const int* in_sizes, int n_in,
                              void* d_out, int out_size, void* d_ws, size_t ws_size,
                              hipStream_t stream) {
  const float* x     = (const float*)d_in[0];
  const float* V     = (const float*)d_in[1];
  const float* W1_0  = (const float*)d_in[2];
  const float* b1_0  = (const float*)d_in[3];
  const float* W2_0  = (const float*)d_in[4];
  const float* b2_0  = (const float*)d_in[5];
  const float* BB_W1 = (const float*)d_in[6];
  const int*   Pi_W1 = (const int*)d_in[7];
  const float* GG_W1 = (const float*)d_in[8];
  const float* BB_b1 = (const float*)d_in[9];
  const int*   Pi_b1 = (const int*)d_in[10];
  const float* GG_b1 = (const float*)d_in[11];
  const float* BB_W2 = (const float*)d_in[12];
  const int*   Pi_W2 = (const int*)d_in[13];
  const float* GG_W2 = (const float*)d_in[14];
  const float* BB_b2 = (const float*)d_in[15];
  const int*   Pi_b2 = (const int*)d_in[16];
  const float* GG_b2 = (const float*)d_in[17];
  float* out = (float*)d_out;

  const size_t MB = 1048576ull;
  char* ws = (char*)d_ws;
  // Layout (72 MB + 40 KB; lifetimes disjoint per dispatch order):
  ushort* W2b = (ushort*)(ws);                 // @0  d1..d11
  ushort* W1b = (ushort*)(ws + 16 * MB);       // @16 d1..d6
  ushort* hH  = (ushort*)(ws + 16 * MB);       // @16 d8..d9 (8MB)
  ushort* w2  = (ushort*)(ws + 24 * MB);       // @24 d10..d12 (4MB)
  ushort* Y   = (ushort*)(ws + 32 * MB);       // @32 Y1 d3..d4, Y2 d7..d9 (16MB)
  float*  PP0 = (float*)(ws + 32 * MB);        // @32 d11..d12 (8MB)
  float*  PP1 = (float*)(ws + 40 * MB);        // @40 d11..d12 (8MB)
  ushort* hb  = (ushort*)(ws + 48 * MB);       // @48 d6..d11 (8MB)
  ushort* v1b = (ushort*)(ws + 56 * MB);       // @56 d4..d6 (8MB)
  float*  P0  = (float*)(ws + 56 * MB);        // @56 d9..d10 (8MB)
  ushort* xb  = (ushort*)(ws + 64 * MB);       // @64 d1..d6 (4MB)
  float*  P1  = (float*)(ws + 64 * MB);        // @64 d9..d10 (8MB, over xb+ub dead)
  ushort* ub  = (ushort*)(ws + 68 * MB);       // @68 d2..d4 (4MB)
  char*   S   = ws + 72 * MB;
  float* t1     = (float*)(S);
  float* t2     = (float*)(S + 4096);
  float* b1     = (float*)(S + 8192);
  float* b2     = (float*)(S + 8192 + 16384);
  float* parts1 = (float*)(S + 8192 + 16384 + 8192);
  float* parts2 = (float*)(S + 8192 + 16384 + 8192 + 4096);

  // d1: cvt x/W1_0/W2_0 -> bf16, t1/t2, bias fastfoods
  prep<<<18436, 256, 0, stream>>>((const float4*)x, (ushort4*)xb,
                                  (const float4*)W1_0, (ushort4*)W1b,
                                  (const float4*)W2_0, (ushort4*)W2b,
                                  V, BB_W1, BB_W2, t1, t2,
                                  BB_b1, Pi_b1, GG_b1, b1_0,
                                  BB_b2, Pi_b2, GG_b2, b2_0, b1, b2);
  // d2: u = rowWHT_2048(x)
  rowwht2048<0, false><<<128, 256, 0, stream>>>(x, nullptr, ub, nullptr);
  // d3: Y1 = gather
  build_z<<<1024, 256, 0, stream>>>(Pi_W1, GG_W1, t1, Y, parts1);
  // d4: v1 = u @ Y1^T  (bf16)
  gemm8<2, 32><<<dim3(32, 8, 1), 512, 0, stream>>>(ub, Y, nullptr, nullptr, v1b, nullptr, nullptr, 1024, 4096, 2048);
  // d5: w1 = sc1 * rowWHT_4096(v1)  (in-place)
  rowwht4096<true><<<256, 256, 0, stream>>>(v1b, v1b, parts1);
  // d6: h = relu(x@W1b^T + w1 + b1)
  gemm8<3, 32><<<dim3(32, 8, 1), 512, 0, stream>>>(xb, W1b, b1, v1b, hb, nullptr, nullptr, 1024, 4096, 2048);
  // d7: Y2 = gather
  build_z<<<1024, 256, 0, stream>>>(Pi_W2, GG_W2, t2, Y, parts2);
  // d8: hH = rowWHT_4096(h)
  rowwht4096<false><<<256, 256, 0, stream>>>(hb, hH, nullptr);
  // d9: v2 planes = hH @ Y2^T  (split-K2, f32 planes)
  gemm8<1, 32><<<dim3(16, 8, 2), 512, 0, stream>>>(hH, Y, nullptr, nullptr, nullptr, P0, P1, 1024, 2048, 4096);
  // d10: w2 = sc2 * rowWHT_2048(P0+P1)
  rowwht2048<2, true><<<128, 256, 0, stream>>>(P0, P1, w2, parts2);
  // d11: out planes = h @ W2b^T  (split-K2, f32 planes)
  gemm8<1, 32><<<dim3(16, 8, 2), 512, 0, stream>>>(hb, W2b, nullptr, nullptr, nullptr, PP0, PP1, 1024, 2048, 4096);
  // d12: out = PP0 + PP1 + w2 + b2
  reduce_out<<<2048, 256, 0, stream>>>((const float4*)PP0, (const float4*)PP1,
                                       (const ushort4*)w2, b2, (float4*)out);
}